// Round 4
// baseline (536.402 us; speedup 1.0000x reference)
//
#include <hip/hip_runtime.h>
#include <hip/hip_bf16.h>
#include <stdint.h>

#define DD 512
#define HW 9216
#define NBATCH 8
#define BN_EPS 1e-5f

typedef __attribute__((ext_vector_type(8))) short short8;
typedef __attribute__((ext_vector_type(4))) float f32x4;

union bf8u { uint32_t u[4]; short8 v; };

__device__ __forceinline__ unsigned short f2bf(float f) {
  union { float f; uint32_t u; } v; v.f = f;
  uint32_t r = v.u + 0x7FFFu + ((v.u >> 16) & 1u);   // RNE
  return (unsigned short)(r >> 16);
}

// ---------------- prep: bf16 weights + folded BN ----------------
__global__ void prep_kernel(const float* __restrict__ W1, const float* __restrict__ W2,
                            const float* __restrict__ s1, const float* __restrict__ b1,
                            const float* __restrict__ m1, const float* __restrict__ v1,
                            const float* __restrict__ s2, const float* __restrict__ b2,
                            const float* __restrict__ m2, const float* __restrict__ v2,
                            unsigned short* __restrict__ W1b, unsigned short* __restrict__ W2b,
                            float* __restrict__ sc1, float* __restrict__ sh1,
                            float* __restrict__ sc2, float* __restrict__ sh2) {
  int t = blockIdx.x * 256 + threadIdx.x;
  if (t < DD * DD) { W1b[t] = f2bf(W1[t]); W2b[t] = f2bf(W2[t]); }
  if (t < DD) {
    float a = s1[t] * rsqrtf(v1[t] + BN_EPS);
    sc1[t] = a; sh1[t] = b1[t] - m1[t] * a;
    float c = s2[t] * rsqrtf(v2[t] + BN_EPS);
    sc2[t] = c; sh2[t] = b2[t] - m2[t] * c;
  }
}

// prep codebooks: CWt[112][512] (transposed concat), CWc[512][128] (native concat, 0-pad)
__global__ void prep_cw(const float* __restrict__ cw1, const float* __restrict__ cw2,
                        const float* __restrict__ cw3,
                        unsigned short* __restrict__ CWt, unsigned short* __restrict__ CWc) {
  int t = blockIdx.x * 256 + threadIdx.x;   // 65536 total
  int d = t >> 7, k = t & 127;
  float v = 0.f;
  if (k < 16) v = cw1[d * 16 + k];
  else if (k < 48) v = cw2[d * 32 + (k - 16)];
  else if (k < 112) v = cw3[d * 64 + (k - 48)];
  unsigned short bv = f2bf(v);
  CWc[d * 128 + k] = bv;
  if (k < 112) CWt[k * 512 + d] = bv;
}

// ---------------- GEMM + BN + ReLU (bf16 MFMA, 128x128 tile, BK=32) ---------
template <int TIN_BF16>
__global__ __launch_bounds__(256) void gemm_bn(
    const void* __restrict__ Xin_, const unsigned short* __restrict__ Wb,
    const float* __restrict__ scale, const float* __restrict__ shift,
    unsigned short* __restrict__ Yout) {
  const int b  = blockIdx.z;
  const int e0 = blockIdx.y * 128;
  const int n0 = blockIdx.x * 128;
  const int tid  = threadIdx.x;
  const int lane = tid & 63;
  const int wave = tid >> 6;
  const int wr = wave >> 1, wc = wave & 1;

  __shared__ __align__(16) unsigned short Alds[128 * 32];
  __shared__ __align__(16) unsigned short Blds[128 * 40];

  const float* Xf          = (const float*)Xin_ + (size_t)b * DD * HW;
  const unsigned short* Xh = (const unsigned short*)Xin_ + (size_t)b * DD * HW;

  f32x4 acc[4][4];
#pragma unroll
  for (int i = 0; i < 4; i++)
#pragma unroll
    for (int j = 0; j < 4; j++) acc[i][j] = (f32x4)0.0f;

  const int arow  = tid >> 1;
  const int ahalf = tid & 1;
  const int bcol  = tid & 127;
  const int bdh   = tid >> 7;

  const int koff = (lane >> 4) * 8;
  const int lrow = lane & 15;

  for (int kt = 0; kt < DD / 32; ++kt) {
    const int d0 = kt * 32;
    __syncthreads();
    {
      const unsigned short* src = Wb + (size_t)(e0 + arow) * DD + d0 + ahalf * 16;
      short8 v0 = *(const short8*)(src);
      short8 v1 = *(const short8*)(src + 8);
      *(short8*)&Alds[arow * 32 + ahalf * 16]     = v0;
      *(short8*)&Alds[arow * 32 + ahalf * 16 + 8] = v1;
    }
    {
      unsigned short* dst = &Blds[bcol * 40 + bdh * 16];
      if (TIN_BF16) {
        const unsigned short* src = Xh + (size_t)(d0 + bdh * 16) * HW + n0 + bcol;
#pragma unroll
        for (int j = 0; j < 8; j++) {
          uint32_t u0 = src[(size_t)(2 * j) * HW];
          uint32_t u1 = src[(size_t)(2 * j + 1) * HW];
          *(uint32_t*)&dst[2 * j] = u0 | (u1 << 16);
        }
      } else {
        const float* src = Xf + (size_t)(d0 + bdh * 16) * HW + n0 + bcol;
#pragma unroll
        for (int j = 0; j < 8; j++) {
          uint32_t u0 = f2bf(src[(size_t)(2 * j) * HW]);
          uint32_t u1 = f2bf(src[(size_t)(2 * j + 1) * HW]);
          *(uint32_t*)&dst[2 * j] = u0 | (u1 << 16);
        }
      }
    }
    __syncthreads();

    short8 af[4], bfr[4];
#pragma unroll
    for (int ma = 0; ma < 4; ma++)
      af[ma] = *(const short8*)&Alds[(wr * 64 + ma * 16 + lrow) * 32 + koff];
#pragma unroll
    for (int nb = 0; nb < 4; nb++)
      bfr[nb] = *(const short8*)&Blds[(wc * 64 + nb * 16 + lrow) * 40 + koff];
#pragma unroll
    for (int ma = 0; ma < 4; ma++)
#pragma unroll
      for (int nb = 0; nb < 4; nb++)
        acc[ma][nb] = __builtin_amdgcn_mfma_f32_16x16x32_bf16(af[ma], bfr[nb], acc[ma][nb], 0, 0, 0);
  }

  const int rbase = (lane >> 4) * 4;
  const int col   = lane & 15;
#pragma unroll
  for (int ma = 0; ma < 4; ma++) {
    const int ebase = e0 + wr * 64 + ma * 16 + rbase;
    float sc[4], sh[4];
#pragma unroll
    for (int r = 0; r < 4; r++) { sc[r] = scale[ebase + r]; sh[r] = shift[ebase + r]; }
#pragma unroll
    for (int nb = 0; nb < 4; nb++) {
      const int n = n0 + wc * 64 + nb * 16 + col;
      const size_t base = (size_t)b * DD * HW + (size_t)ebase * HW + n;
#pragma unroll
      for (int r = 0; r < 4; r++) {
        float y = acc[ma][nb][r] * sc[r] + sh[r];
        y = y > 0.f ? y : 0.f;
        Yout[base + (size_t)r * HW] = f2bf(y);
      }
    }
  }
}

// ---------------- fused soft-VQ x3 via MFMA + final add (v2) ----------------
// Block: 64 positions, 4 waves; wave wv owns positions n0+16*wv..+15.
// Phase 1 (no LDS, no barriers): L^T[code][pos] = CWt @ X; A-frags direct from
// global CWt (L2-resident), B-frags direct from global X/X2/X3 (native [d][n]
// layout IS the B-fragment layout). Phase 2: softmax, 2 shuffles (xor16,32).
// Phase 3: E = CWc @ P'^T; A-frags direct from global CWc, B-frags from Pl LDS.
__global__ __launch_bounds__(256) void vq_mfma(
    const float* __restrict__ X, const unsigned short* __restrict__ X2,
    const unsigned short* __restrict__ X3,
    const unsigned short* __restrict__ CWt,   // [112][512]
    const unsigned short* __restrict__ CWc,   // [512][128]
    const float* __restrict__ gg1, const float* __restrict__ gg2,
    const float* __restrict__ gg3, float* __restrict__ out) {
  const int b  = blockIdx.y;
  const int n0 = blockIdx.x * 64;
  const int tid  = threadIdx.x;
  const int lane = tid & 63;
  const int wv   = tid >> 6;
  const int hi = lane >> 4, lr = lane & 15;

  __shared__ __align__(16) unsigned short Pl[64 * 136];   // P' [pos][code(128)]

  const size_t bbase = (size_t)b * DD * HW;
  const int myn = n0 + wv * 16 + lr;
  const float*          pX  = X  + bbase + myn;
  const unsigned short* pX2 = X2 + bbase + myn;
  const unsigned short* pX3 = X3 + bbase + myn;

  f32x4 accl[7];
#pragma unroll
  for (int t = 0; t < 7; t++) accl[t] = (f32x4)0.0f;

  // ---------- phase 1: logits (barrier-free) ----------
  for (int kt = 0; kt < 16; ++kt) {
    const int d0 = kt * 32;
    const size_t rbase = (size_t)(d0 + hi * 8) * HW;

    bf8u bx, b2, b3;
#pragma unroll
    for (int j = 0; j < 4; j++) {
      uint32_t u0 = f2bf(pX[rbase + (size_t)(2 * j) * HW]);
      uint32_t u1 = f2bf(pX[rbase + (size_t)(2 * j + 1) * HW]);
      bx.u[j] = u0 | (u1 << 16);
    }
#pragma unroll
    for (int j = 0; j < 4; j++) {
      uint32_t u0 = pX2[rbase + (size_t)(2 * j) * HW];
      uint32_t u1 = pX2[rbase + (size_t)(2 * j + 1) * HW];
      b2.u[j] = u0 | (u1 << 16);
    }
#pragma unroll
    for (int j = 0; j < 4; j++) {
      uint32_t u0 = pX3[rbase + (size_t)(2 * j) * HW];
      uint32_t u1 = pX3[rbase + (size_t)(2 * j + 1) * HW];
      b3.u[j] = u0 | (u1 << 16);
    }

    short8 at[7];
#pragma unroll
    for (int t = 0; t < 7; t++)
      at[t] = *(const short8*)&CWt[(size_t)(t * 16 + lr) * 512 + d0 + hi * 8];

    accl[0] = __builtin_amdgcn_mfma_f32_16x16x32_bf16(at[0], bx.v, accl[0], 0, 0, 0);
    accl[1] = __builtin_amdgcn_mfma_f32_16x16x32_bf16(at[1], b2.v, accl[1], 0, 0, 0);
    accl[2] = __builtin_amdgcn_mfma_f32_16x16x32_bf16(at[2], b2.v, accl[2], 0, 0, 0);
#pragma unroll
    for (int t = 3; t < 7; t++)
      accl[t] = __builtin_amdgcn_mfma_f32_16x16x32_bf16(at[t], b3.v, accl[t], 0, 0, 0);
  }

  // ---------- phase 2: softmax over codes (lane = one position) ----------
  // lane (hi,lr) holds codes 16t+4hi+r for pos myn; reduce across hi via xor16/32.
  {
    const float gv1 = gg1[0], gv2 = gg2[0], gv3 = gg3[0];
    const int prow = (wv * 16 + lr) * 136;
    {  // cb1: tile 0
      float m = fmaxf(fmaxf(accl[0][0], accl[0][1]), fmaxf(accl[0][2], accl[0][3]));
      m = fmaxf(m, __shfl_xor(m, 16, 64));
      m = fmaxf(m, __shfl_xor(m, 32, 64));
      float e[4], s = 0.f;
#pragma unroll
      for (int r = 0; r < 4; r++) { e[r] = __expf(accl[0][r] - m); s += e[r]; }
      s += __shfl_xor(s, 16, 64);
      s += __shfl_xor(s, 32, 64);
      float sc = gv1 / s;
#pragma unroll
      for (int r = 0; r < 4; r++) Pl[prow + 4 * hi + r] = f2bf(e[r] * sc);
    }
    {  // cb2: tiles 1,2
      float m = accl[1][0];
#pragma unroll
      for (int r = 1; r < 4; r++) m = fmaxf(m, accl[1][r]);
#pragma unroll
      for (int r = 0; r < 4; r++) m = fmaxf(m, accl[2][r]);
      m = fmaxf(m, __shfl_xor(m, 16, 64));
      m = fmaxf(m, __shfl_xor(m, 32, 64));
      float e1[4], e2[4], s = 0.f;
#pragma unroll
      for (int r = 0; r < 4; r++) { e1[r] = __expf(accl[1][r] - m); s += e1[r]; }
#pragma unroll
      for (int r = 0; r < 4; r++) { e2[r] = __expf(accl[2][r] - m); s += e2[r]; }
      s += __shfl_xor(s, 16, 64);
      s += __shfl_xor(s, 32, 64);
      float sc = gv2 / s;
#pragma unroll
      for (int r = 0; r < 4; r++) {
        Pl[prow + 16 + 4 * hi + r] = f2bf(e1[r] * sc);
        Pl[prow + 32 + 4 * hi + r] = f2bf(e2[r] * sc);
      }
    }
    {  // cb3: tiles 3..6
      float m = accl[3][0];
#pragma unroll
      for (int t = 3; t < 7; t++)
#pragma unroll
        for (int r = 0; r < 4; r++) m = fmaxf(m, accl[t][r]);
      m = fmaxf(m, __shfl_xor(m, 16, 64));
      m = fmaxf(m, __shfl_xor(m, 32, 64));
      float e[4][4], s = 0.f;
#pragma unroll
      for (int t = 0; t < 4; t++)
#pragma unroll
        for (int r = 0; r < 4; r++) { e[t][r] = __expf(accl[3 + t][r] - m); s += e[t][r]; }
      s += __shfl_xor(s, 16, 64);
      s += __shfl_xor(s, 32, 64);
      float sc = gv3 / s;
#pragma unroll
      for (int t = 0; t < 4; t++)
#pragma unroll
        for (int r = 0; r < 4; r++)
          Pl[prow + 48 + 16 * t + 4 * hi + r] = f2bf(e[t][r] * sc);
    }
    // zero pad codes 112..127 (64 pos x 16)
    {
      int pp = tid & 63, cg = tid >> 6;
      *(uint64_t*)&Pl[pp * 136 + 112 + cg * 4] = 0;
    }
  }
  __syncthreads();

  // ---------- phase 3: E = CWc @ P'^T, fused X + E ----------
  short8 pf[4][4];
#pragma unroll
  for (int ct = 0; ct < 4; ++ct)
#pragma unroll
    for (int s = 0; s < 4; ++s)
      pf[ct][s] = *(const short8*)&Pl[(ct * 16 + lr) * 136 + s * 32 + hi * 8];

  const float* Xg = X + bbase;
  float* outg = out + bbase;
#pragma unroll 2
  for (int dt = wv; dt < 32; dt += 4) {
    f32x4 acc3[4];
#pragma unroll
    for (int ct = 0; ct < 4; ++ct) acc3[ct] = (f32x4)0.0f;
#pragma unroll
    for (int s = 0; s < 4; ++s) {
      short8 af = *(const short8*)&CWc[(size_t)(dt * 16 + lr) * 128 + s * 32 + hi * 8];
#pragma unroll
      for (int ct = 0; ct < 4; ++ct)
        acc3[ct] = __builtin_amdgcn_mfma_f32_16x16x32_bf16(af, pf[ct][s], acc3[ct], 0, 0, 0);
    }
    const int dgb = dt * 16 + 4 * hi;
#pragma unroll
    for (int ct = 0; ct < 4; ++ct) {
      const int n = n0 + ct * 16 + lr;
#pragma unroll
      for (int r = 0; r < 4; ++r) {
        const size_t a = (size_t)(dgb + r) * HW + n;
        outg[a] = Xg[a] + acc3[ct][r];
      }
    }
  }
}

extern "C" void kernel_launch(void* const* d_in, const int* in_sizes, int n_in,
                              void* d_out, int out_size, void* d_ws, size_t ws_size,
                              hipStream_t stream) {
  const float* X    = (const float*)d_in[0];
  const float* W1   = (const float*)d_in[1];
  const float* bn1s = (const float*)d_in[2];
  const float* bn1b = (const float*)d_in[3];
  const float* bn1m = (const float*)d_in[4];
  const float* bn1v = (const float*)d_in[5];
  const float* W2   = (const float*)d_in[6];
  const float* bn2s = (const float*)d_in[7];
  const float* bn2b = (const float*)d_in[8];
  const float* bn2m = (const float*)d_in[9];
  const float* bn2v = (const float*)d_in[10];
  const float* cw1  = (const float*)d_in[11];
  const float* cw2  = (const float*)d_in[12];
  const float* cw3  = (const float*)d_in[13];
  const float* g1   = (const float*)d_in[14];
  const float* g2   = (const float*)d_in[15];
  const float* g3   = (const float*)d_in[16];

  // ws: W1b(512K) | W2b(512K) | scales(8K) | CWt(112K) | CWc(128K) | X2(72M) | X3(72M)
  char* ws = (char*)d_ws;
  unsigned short* W1b = (unsigned short*)(ws);
  unsigned short* W2b = (unsigned short*)(ws + 524288);
  float* sc1 = (float*)(ws + 1048576);
  float* sh1 = sc1 + 512;
  float* sc2 = sh1 + 512;
  float* sh2 = sc2 + 512;
  unsigned short* CWt = (unsigned short*)(ws + 1064960);
  unsigned short* CWc = (unsigned short*)(ws + 1064960 + 114688);
  unsigned short* X2 = (unsigned short*)(ws + (1 << 21));
  unsigned short* X3 = X2 + (size_t)NBATCH * DD * HW;

  prep_kernel<<<1024, 256, 0, stream>>>(W1, W2, bn1s, bn1b, bn1m, bn1v,
                                        bn2s, bn2b, bn2m, bn2v,
                                        W1b, W2b, sc1, sh1, sc2, sh2);
  prep_cw<<<256, 256, 0, stream>>>(cw1, cw2, cw3, CWt, CWc);

  dim3 gg(HW / 128, DD / 128, NBATCH);
  gemm_bn<0><<<gg, 256, 0, stream>>>((const void*)X,  W1b, sc1, sh1, X2);
  gemm_bn<1><<<gg, 256, 0, stream>>>((const void*)X2, W2b, sc2, sh2, X3);

  dim3 gv(HW / 64, NBATCH);   // (144, 8)
  vq_mfma<<<gv, 256, 0, stream>>>(X, X2, X3, CWt, CWc, g1, g2, g3, (float*)d_out);
}

// Round 5
// 351.227 us; speedup vs baseline: 1.5272x; 1.5272x over previous
//
#include <hip/hip_runtime.h>
#include <hip/hip_bf16.h>
#include <stdint.h>

#define DD 512
#define HW 9216
#define NBATCH 8
#define BN_EPS 1e-5f

typedef __attribute__((ext_vector_type(8))) short short8;
typedef __attribute__((ext_vector_type(4))) float f32x4;

__device__ __forceinline__ unsigned short f2bf(float f) {
  union { float f; uint32_t u; } v; v.f = f;
  uint32_t r = v.u + 0x7FFFu + ((v.u >> 16) & 1u);   // RNE
  return (unsigned short)(r >> 16);
}

// ---------------- prep: bf16 weights + folded BN ----------------
__global__ void prep_kernel(const float* __restrict__ W1, const float* __restrict__ W2,
                            const float* __restrict__ s1, const float* __restrict__ b1,
                            const float* __restrict__ m1, const float* __restrict__ v1,
                            const float* __restrict__ s2, const float* __restrict__ b2,
                            const float* __restrict__ m2, const float* __restrict__ v2,
                            unsigned short* __restrict__ W1b, unsigned short* __restrict__ W2b,
                            float* __restrict__ sc1, float* __restrict__ sh1,
                            float* __restrict__ sc2, float* __restrict__ sh2) {
  int t = blockIdx.x * 256 + threadIdx.x;
  if (t < DD * DD) { W1b[t] = f2bf(W1[t]); W2b[t] = f2bf(W2[t]); }
  if (t < DD) {
    float a = s1[t] * rsqrtf(v1[t] + BN_EPS);
    sc1[t] = a; sh1[t] = b1[t] - m1[t] * a;
    float c = s2[t] * rsqrtf(v2[t] + BN_EPS);
    sc2[t] = c; sh2[t] = b2[t] - m2[t] * c;
  }
}

// prep codebooks: CWt[112][512] (transposed concat), CWc[512][128] (native concat, 0-pad)
__global__ void prep_cw(const float* __restrict__ cw1, const float* __restrict__ cw2,
                        const float* __restrict__ cw3,
                        unsigned short* __restrict__ CWt, unsigned short* __restrict__ CWc) {
  int t = blockIdx.x * 256 + threadIdx.x;   // 65536 total
  int d = t >> 7, k = t & 127;
  float v = 0.f;
  if (k < 16) v = cw1[d * 16 + k];
  else if (k < 48) v = cw2[d * 32 + (k - 16)];
  else if (k < 112) v = cw3[d * 64 + (k - 48)];
  unsigned short bv = f2bf(v);
  CWc[d * 128 + k] = bv;
  if (k < 112) CWt[k * 512 + d] = bv;
}

// ---------------- GEMM + BN + ReLU (bf16 MFMA, 128x128 tile, BK=32) ---------
template <int TIN_BF16>
__global__ __launch_bounds__(256) void gemm_bn(
    const void* __restrict__ Xin_, const unsigned short* __restrict__ Wb,
    const float* __restrict__ scale, const float* __restrict__ shift,
    unsigned short* __restrict__ Yout) {
  const int b  = blockIdx.z;
  const int e0 = blockIdx.y * 128;
  const int n0 = blockIdx.x * 128;
  const int tid  = threadIdx.x;
  const int lane = tid & 63;
  const int wave = tid >> 6;
  const int wr = wave >> 1, wc = wave & 1;

  __shared__ __align__(16) unsigned short Alds[128 * 32];
  __shared__ __align__(16) unsigned short Blds[128 * 40];

  const float* Xf          = (const float*)Xin_ + (size_t)b * DD * HW;
  const unsigned short* Xh = (const unsigned short*)Xin_ + (size_t)b * DD * HW;

  f32x4 acc[4][4];
#pragma unroll
  for (int i = 0; i < 4; i++)
#pragma unroll
    for (int j = 0; j < 4; j++) acc[i][j] = (f32x4)0.0f;

  const int arow  = tid >> 1;
  const int ahalf = tid & 1;
  const int bcol  = tid & 127;
  const int bdh   = tid >> 7;

  const int koff = (lane >> 4) * 8;
  const int lrow = lane & 15;

  for (int kt = 0; kt < DD / 32; ++kt) {
    const int d0 = kt * 32;
    __syncthreads();
    {
      const unsigned short* src = Wb + (size_t)(e0 + arow) * DD + d0 + ahalf * 16;
      short8 v0 = *(const short8*)(src);
      short8 v1 = *(const short8*)(src + 8);
      *(short8*)&Alds[arow * 32 + ahalf * 16]     = v0;
      *(short8*)&Alds[arow * 32 + ahalf * 16 + 8] = v1;
    }
    {
      unsigned short* dst = &Blds[bcol * 40 + bdh * 16];
      if (TIN_BF16) {
        const unsigned short* src = Xh + (size_t)(d0 + bdh * 16) * HW + n0 + bcol;
#pragma unroll
        for (int j = 0; j < 8; j++) {
          uint32_t u0 = src[(size_t)(2 * j) * HW];
          uint32_t u1 = src[(size_t)(2 * j + 1) * HW];
          *(uint32_t*)&dst[2 * j] = u0 | (u1 << 16);
        }
      } else {
        const float* src = Xf + (size_t)(d0 + bdh * 16) * HW + n0 + bcol;
#pragma unroll
        for (int j = 0; j < 8; j++) {
          uint32_t u0 = f2bf(src[(size_t)(2 * j) * HW]);
          uint32_t u1 = f2bf(src[(size_t)(2 * j + 1) * HW]);
          *(uint32_t*)&dst[2 * j] = u0 | (u1 << 16);
        }
      }
    }
    __syncthreads();

    short8 af[4], bfr[4];
#pragma unroll
    for (int ma = 0; ma < 4; ma++)
      af[ma] = *(const short8*)&Alds[(wr * 64 + ma * 16 + lrow) * 32 + koff];
#pragma unroll
    for (int nb = 0; nb < 4; nb++)
      bfr[nb] = *(const short8*)&Blds[(wc * 64 + nb * 16 + lrow) * 40 + koff];
#pragma unroll
    for (int ma = 0; ma < 4; ma++)
#pragma unroll
      for (int nb = 0; nb < 4; nb++)
        acc[ma][nb] = __builtin_amdgcn_mfma_f32_16x16x32_bf16(af[ma], bfr[nb], acc[ma][nb], 0, 0, 0);
  }

  const int rbase = (lane >> 4) * 4;
  const int col   = lane & 15;
#pragma unroll
  for (int ma = 0; ma < 4; ma++) {
    const int ebase = e0 + wr * 64 + ma * 16 + rbase;
    float sc[4], sh[4];
#pragma unroll
    for (int r = 0; r < 4; r++) { sc[r] = scale[ebase + r]; sh[r] = shift[ebase + r]; }
#pragma unroll
    for (int nb = 0; nb < 4; nb++) {
      const int n = n0 + wc * 64 + nb * 16 + col;
      const size_t base = (size_t)b * DD * HW + (size_t)ebase * HW + n;
#pragma unroll
      for (int r = 0; r < 4; r++) {
        float y = acc[ma][nb][r] * sc[r] + sh[r];
        y = y > 0.f ? y : 0.f;
        Yout[base + (size_t)r * HW] = f2bf(y);
      }
    }
  }
}

// ---------------- fused soft-VQ x3 via MFMA + final add (v5) ----------------
// Revert to v3's LDS-staged structure with: (a) conflict-free chunked LDS
// layouts [kchunk][row][16B] (all b128 ops at the 1KB/wave floor), (b) LDS
// aliasing (P', CWc chunks reuse the phase-1 region) -> 19.5 KB total,
// (c) T14 register prefetch: kt+1 global loads issued under kt's MFMAs.
__global__ __launch_bounds__(256, 4) void vq_mfma(
    const float* __restrict__ X, const unsigned short* __restrict__ X2,
    const unsigned short* __restrict__ X3,
    const unsigned short* __restrict__ CWt,   // [112][512]
    const unsigned short* __restrict__ CWc,   // [512][128]
    const float* __restrict__ gg1, const float* __restrict__ gg2,
    const float* __restrict__ gg3, float* __restrict__ out) {
  const int b  = blockIdx.y;
  const int n0 = blockIdx.x * 64;
  const int tid  = threadIdx.x;
  const int lane = tid & 63;
  const int wv   = tid >> 6;
  const int hi = lane >> 4, lr = lane & 15;

  // one pool, manually aliased (ushort offsets):
  // ph1: XS0 @0, XS1 @2048, XS2 @4096  each [dchunk4][pos64][8]  (2048 ea)
  //      CWtS @6144 [dchunk4][code112][8] (3584)                  -> 9728 total
  // ph2/3 (aliased @0): Pl [oct16][pos64][8] (8192); then CWcS same shape.
  __shared__ __align__(16) unsigned short LDS[9728];   // 19456 B

  const size_t bbase = (size_t)b * DD * HW;
  const int sn = lane, sg = wv;  // staging: all 256 threads, pos sn, d-group sg
  const float*          pXs  = X  + bbase + (size_t)(sg * 8) * HW + n0 + sn;
  const unsigned short* pX2s = X2 + bbase + (size_t)(sg * 8) * HW + n0 + sn;
  const unsigned short* pX3s = X3 + bbase + (size_t)(sg * 8) * HW + n0 + sn;
  // CWt staging: threads t<224 stage units i=2t,2t+1: code=i>>2, dchunk=i&3
  const int  cwt_on = (tid < 224);
  const int  ccode  = tid >> 1;            // code for both units
  const int  cdk0   = (2 * tid) & 3;       // in {0,2}
  const int  cdk1   = (2 * tid + 1) & 3;   // in {1,3}

  float    rx[8];
  uint32_t r2[8], r3[8];
  short8   rc0, rc1;

  auto vq_loads = [&](int kt) {
    const int d0 = kt * 32;
#pragma unroll
    for (int j = 0; j < 8; j++) rx[j] = pXs[(size_t)(d0 + j) * HW];
#pragma unroll
    for (int j = 0; j < 8; j++) r2[j] = pX2s[(size_t)(d0 + j) * HW];
#pragma unroll
    for (int j = 0; j < 8; j++) r3[j] = pX3s[(size_t)(d0 + j) * HW];
    if (cwt_on) {
      rc0 = *(const short8*)&CWt[(size_t)ccode * 512 + d0 + cdk0 * 8];
      rc1 = *(const short8*)&CWt[(size_t)ccode * 512 + d0 + cdk1 * 8];
    }
  };
  auto vq_store = [&]() {
    union { uint32_t u[4]; short8 v; } px, p2, p3;
#pragma unroll
    for (int j = 0; j < 4; j++) {
      px.u[j] = (uint32_t)f2bf(rx[2 * j]) | ((uint32_t)f2bf(rx[2 * j + 1]) << 16);
      p2.u[j] = r2[2 * j] | (r2[2 * j + 1] << 16);
      p3.u[j] = r3[2 * j] | (r3[2 * j + 1] << 16);
    }
    *(short8*)&LDS[       sg * 512 + sn * 8] = px.v;
    *(short8*)&LDS[2048 + sg * 512 + sn * 8] = p2.v;
    *(short8*)&LDS[4096 + sg * 512 + sn * 8] = p3.v;
    if (cwt_on) {
      *(short8*)&LDS[6144 + cdk0 * 896 + ccode * 8] = rc0;
      *(short8*)&LDS[6144 + cdk1 * 896 + ccode * 8] = rc1;
    }
  };

  f32x4 accl[7];
#pragma unroll
  for (int t = 0; t < 7; t++) accl[t] = (f32x4)0.0f;

  // ---------- phase 1: logits (prefetch-pipelined) ----------
  vq_loads(0);
  for (int kt = 0; kt < 16; ++kt) {
    __syncthreads();                 // prev iter's frag reads done
    vq_store();
    if (kt < 15) vq_loads(kt + 1);   // fly under frag reads + MFMAs
    __syncthreads();                 // staging visible

    short8 a0 = *(const short8*)&LDS[       hi * 512 + (wv * 16 + lr) * 8];
    short8 a1 = *(const short8*)&LDS[2048 + hi * 512 + (wv * 16 + lr) * 8];
    short8 a2 = *(const short8*)&LDS[4096 + hi * 512 + (wv * 16 + lr) * 8];
    short8 bt[7];
#pragma unroll
    for (int t = 0; t < 7; t++)
      bt[t] = *(const short8*)&LDS[6144 + hi * 896 + (t * 16 + lr) * 8];
    accl[0] = __builtin_amdgcn_mfma_f32_16x16x32_bf16(a0, bt[0], accl[0], 0, 0, 0);
    accl[1] = __builtin_amdgcn_mfma_f32_16x16x32_bf16(a1, bt[1], accl[1], 0, 0, 0);
    accl[2] = __builtin_amdgcn_mfma_f32_16x16x32_bf16(a1, bt[2], accl[2], 0, 0, 0);
#pragma unroll
    for (int t = 3; t < 7; t++)
      accl[t] = __builtin_amdgcn_mfma_f32_16x16x32_bf16(a2, bt[t], accl[t], 0, 0, 0);
  }
  __syncthreads();   // phase-1 region dead; P' may now alias it

  // ---------- phase 2: softmax (lane holds pos = wv*16+4*hi+r, code = 16t+lr) ----
  // P' layout [oct16][pos64][8]: oct = 2t + (lr>>3), slot = lr&7.
  {
    const float gv1 = gg1[0], gv2 = gg2[0], gv3 = gg3[0];
    const int pbase = (wv * 16 + 4 * hi) * 8 + (lr & 7);
    const int o8 = (lr >> 3) * 512;
    {  // cb1: tile 0
      float m = fmaxf(fmaxf(accl[0][0], accl[0][1]), fmaxf(accl[0][2], accl[0][3]));
#pragma unroll
      for (int mk = 1; mk <= 8; mk <<= 1) m = fmaxf(m, __shfl_xor(m, mk, 64));
      float e[4], s = 0.f;
#pragma unroll
      for (int r = 0; r < 4; r++) { e[r] = __expf(accl[0][r] - m); s += e[r]; }
#pragma unroll
      for (int mk = 1; mk <= 8; mk <<= 1) s += __shfl_xor(s, mk, 64);
      float sc = gv1 / s;
#pragma unroll
      for (int r = 0; r < 4; r++) LDS[o8 + pbase + r * 8] = f2bf(e[r] * sc);
    }
    {  // cb2: tiles 1,2
      float m = accl[1][0];
#pragma unroll
      for (int r = 1; r < 4; r++) m = fmaxf(m, accl[1][r]);
#pragma unroll
      for (int r = 0; r < 4; r++) m = fmaxf(m, accl[2][r]);
#pragma unroll
      for (int mk = 1; mk <= 8; mk <<= 1) m = fmaxf(m, __shfl_xor(m, mk, 64));
      float e1[4], e2[4], s = 0.f;
#pragma unroll
      for (int r = 0; r < 4; r++) { e1[r] = __expf(accl[1][r] - m); s += e1[r]; }
#pragma unroll
      for (int r = 0; r < 4; r++) { e2[r] = __expf(accl[2][r] - m); s += e2[r]; }
#pragma unroll
      for (int mk = 1; mk <= 8; mk <<= 1) s += __shfl_xor(s, mk, 64);
      float sc = gv2 / s;
#pragma unroll
      for (int r = 0; r < 4; r++) {
        LDS[(2 * 1) * 512 + o8 + pbase + r * 8] = f2bf(e1[r] * sc);
        LDS[(2 * 2) * 512 + o8 + pbase + r * 8] = f2bf(e2[r] * sc);
      }
    }
    {  // cb3: tiles 3..6
      float m = accl[3][0];
#pragma unroll
      for (int t = 3; t < 7; t++)
#pragma unroll
        for (int r = 0; r < 4; r++) m = fmaxf(m, accl[t][r]);
#pragma unroll
      for (int mk = 1; mk <= 8; mk <<= 1) m = fmaxf(m, __shfl_xor(m, mk, 64));
      float e[4][4], s = 0.f;
#pragma unroll
      for (int t = 0; t < 4; t++)
#pragma unroll
        for (int r = 0; r < 4; r++) { e[t][r] = __expf(accl[3 + t][r] - m); s += e[t][r]; }
#pragma unroll
      for (int mk = 1; mk <= 8; mk <<= 1) s += __shfl_xor(s, mk, 64);
      float sc = gv3 / s;
#pragma unroll
      for (int t = 0; t < 4; t++)
#pragma unroll
        for (int r = 0; r < 4; r++)
          LDS[(2 * (3 + t)) * 512 + o8 + pbase + r * 8] = f2bf(e[t][r] * sc);
    }
    // zero pad: octs 14,15 (codes 112..127)
    if (tid < 128) *(short8*)&LDS[7168 + tid * 8] = (short8)0;
  }
  __syncthreads();   // P' complete

  // pf frags: B-operand of recon GEMM: col=pos (ct*16+lr), k=code (s*32+hi*8+j)
  short8 pf[4][4];
#pragma unroll
  for (int ct = 0; ct < 4; ++ct)
#pragma unroll
    for (int s = 0; s < 4; ++s)
      pf[ct][s] = *(const short8*)&LDS[(4 * s + hi) * 512 + (ct * 16 + lr) * 8];

  // CWc chunk prefetch: thread covers drow=tid>>2, octs (tid&3)+4j (j<4)
  short8 rcc[4];
  auto cwc_loads = [&](int c) {
#pragma unroll
    for (int j = 0; j < 4; j++)
      rcc[j] = *(const short8*)&CWc[(size_t)(c * 64 + (tid >> 2)) * 128 + ((tid & 3) + 4 * j) * 8];
  };
  cwc_loads(0);

  const float* Xg = X + bbase;
  float* outg = out + bbase;
  for (int c = 0; c < 8; ++c) {
    __syncthreads();   // pf reads done (c=0) / prev af reads done
#pragma unroll
    for (int j = 0; j < 4; j++)
      *(short8*)&LDS[((tid & 3) + 4 * j) * 512 + (tid >> 2) * 8] = rcc[j];
    if (c < 7) cwc_loads(c + 1);
    __syncthreads();

    // wave wv handles d-tile dt = 4c+wv (rows wv*16..+15 of the chunk)
    f32x4 acc3[4];
#pragma unroll
    for (int ct = 0; ct < 4; ++ct) acc3[ct] = (f32x4)0.0f;
#pragma unroll
    for (int s = 0; s < 4; ++s) {
      short8 af = *(const short8*)&LDS[(4 * s + hi) * 512 + (wv * 16 + lr) * 8];
#pragma unroll
      for (int ct = 0; ct < 4; ++ct)
        acc3[ct] = __builtin_amdgcn_mfma_f32_16x16x32_bf16(af, pf[ct][s], acc3[ct], 0, 0, 0);
    }
    const int dgb = (4 * c + wv) * 16 + 4 * hi;
#pragma unroll
    for (int ct = 0; ct < 4; ++ct) {
      const int n = n0 + ct * 16 + lr;
#pragma unroll
      for (int r = 0; r < 4; ++r) {
        const size_t a = (size_t)(dgb + r) * HW + n;
        outg[a] = Xg[a] + acc3[ct][r];
      }
    }
  }
}

extern "C" void kernel_launch(void* const* d_in, const int* in_sizes, int n_in,
                              void* d_out, int out_size, void* d_ws, size_t ws_size,
                              hipStream_t stream) {
  const float* X    = (const float*)d_in[0];
  const float* W1   = (const float*)d_in[1];
  const float* bn1s = (const float*)d_in[2];
  const float* bn1b = (const float*)d_in[3];
  const float* bn1m = (const float*)d_in[4];
  const float* bn1v = (const float*)d_in[5];
  const float* W2   = (const float*)d_in[6];
  const float* bn2s = (const float*)d_in[7];
  const float* bn2b = (const float*)d_in[8];
  const float* bn2m = (const float*)d_in[9];
  const float* bn2v = (const float*)d_in[10];
  const float* cw1  = (const float*)d_in[11];
  const float* cw2  = (const float*)d_in[12];
  const float* cw3  = (const float*)d_in[13];
  const float* g1   = (const float*)d_in[14];
  const float* g2   = (const float*)d_in[15];
  const float* g3   = (const float*)d_in[16];

  // ws: W1b(512K) | W2b(512K) | scales(8K) | CWt(112K) | CWc(128K) | X2(72M) | X3(72M)
  char* ws = (char*)d_ws;
  unsigned short* W1b = (unsigned short*)(ws);
  unsigned short* W2b = (unsigned short*)(ws + 524288);
  float* sc1 = (float*)(ws + 1048576);
  float* sh1 = sc1 + 512;
  float* sc2 = sh1 + 512;
  float* sh2 = sc2 + 512;
  unsigned short* CWt = (unsigned short*)(ws + 1064960);
  unsigned short* CWc = (unsigned short*)(ws + 1064960 + 114688);
  unsigned short* X2 = (unsigned short*)(ws + (1 << 21));
  unsigned short* X3 = X2 + (size_t)NBATCH * DD * HW;

  prep_kernel<<<1024, 256, 0, stream>>>(W1, W2, bn1s, bn1b, bn1m, bn1v,
                                        bn2s, bn2b, bn2m, bn2v,
                                        W1b, W2b, sc1, sh1, sc2, sh2);
  prep_cw<<<256, 256, 0, stream>>>(cw1, cw2, cw3, CWt, CWc);

  dim3 gg(HW / 128, DD / 128, NBATCH);
  gemm_bn<0><<<gg, 256, 0, stream>>>((const void*)X,  W1b, sc1, sh1, X2);
  gemm_bn<1><<<gg, 256, 0, stream>>>((const void*)X2, W2b, sc2, sh2, X3);

  dim3 gv(HW / 64, NBATCH);   // (144, 8)
  vq_mfma<<<gv, 256, 0, stream>>>(X, X2, X3, CWt, CWc, g1, g2, g3, (float*)d_out);
}